// Round 3
// baseline (1919.685 us; speedup 1.0000x reference)
//
#include <hip/hip_runtime.h>
#include <hip/hip_bf16.h>
#include <type_traits>

typedef __hip_bfloat16 bf16;
typedef __attribute__((ext_vector_type(8))) short s8v;   // 8 x bf16 (16B)
typedef __attribute__((ext_vector_type(4))) float f4v;   // MFMA C/D frag

#define MFMA16(A, B, C) __builtin_amdgcn_mfma_f32_16x16x32_bf16((A), (B), (C), 0, 0, 0)

constexpr int SEQ = 2048;
constexpr int DIM = 4096;
constexpr int NH  = 32;
constexpr int HD  = 128;

__device__ __forceinline__ short f2bs(float f) {
    __hip_bfloat16_raw r = __float2bfloat16(f);
    return (short)r.x;
}

// ---------------------------------------------------------------------------
// GEMM: C[M,N] = A[M,K] * B[K,N].  A: fp32 or bf16 (template). B: fp32,
// converted to bf16 during LDS staging (in-LDS transpose to [n][k]).
// C: fp32 or bf16 (template). fp32 accumulate via bf16 MFMA.
// 128x128 tile, BK=32, 256 threads = 4 waves 2x2, wave = 64x64 (4x4 MFMA).
// ---------------------------------------------------------------------------
template <typename AT, typename CT>
__global__ __launch_bounds__(256) void gemm_nat(const AT* __restrict__ A,
                                                const float* __restrict__ B,
                                                CT* __restrict__ C,
                                                int M, int N, int K) {
    __shared__ short As[128][40];   // As[m][k], +8 pad
    __shared__ short Bs[128][40];   // Bs[n][k], +8 pad
    const int tid  = threadIdx.x;
    const int lane = tid & 63;
    const int w    = tid >> 6;
    const int m16  = lane & 15;
    const int quad = lane >> 4;
    const int wm   = w >> 1, wn = w & 1;
    const int bm   = blockIdx.y, bn = blockIdx.x;

    const AT* Ab = A + (size_t)bm * 128 * K;

    f4v acc[4][4] = {};
    const int r0 = tid >> 2;
    const int kc = (tid & 3) * 8;

    for (int k0 = 0; k0 < K; k0 += 32) {
        // ---- A tile: 128 rows x 32 k ----
        if constexpr (std::is_same<AT, float>::value) {
#pragma unroll
            for (int half = 0; half < 2; half++) {
                const float* src = Ab + (size_t)(r0 + 64 * half) * K + k0 + kc;
                float4 f0 = *(const float4*)(src);
                float4 f1 = *(const float4*)(src + 4);
                s8v t;
                t[0] = f2bs(f0.x); t[1] = f2bs(f0.y); t[2] = f2bs(f0.z); t[3] = f2bs(f0.w);
                t[4] = f2bs(f1.x); t[5] = f2bs(f1.y); t[6] = f2bs(f1.z); t[7] = f2bs(f1.w);
                *(s8v*)&As[r0 + 64 * half][kc] = t;
            }
        } else {
            *(s8v*)&As[r0][kc]      = *(const s8v*)(Ab + (size_t)r0 * K + k0 + kc);
            *(s8v*)&As[r0 + 64][kc] = *(const s8v*)(Ab + (size_t)(r0 + 64) * K + k0 + kc);
        }
        // ---- B tile: 32 k-rows x 128 n-cols, coalesced fp32 read, transpose ----
#pragma unroll
        for (int v = tid; v < 512; v += 256) {
            int kr = v >> 4;            // 0..31
            int nc = (v & 15) * 8;      // 0..120
            const float* src = B + (size_t)(k0 + kr) * N + bn * 128 + nc;
            float4 f0 = *(const float4*)(src);
            float4 f1 = *(const float4*)(src + 4);
            Bs[nc + 0][kr] = f2bs(f0.x); Bs[nc + 1][kr] = f2bs(f0.y);
            Bs[nc + 2][kr] = f2bs(f0.z); Bs[nc + 3][kr] = f2bs(f0.w);
            Bs[nc + 4][kr] = f2bs(f1.x); Bs[nc + 5][kr] = f2bs(f1.y);
            Bs[nc + 6][kr] = f2bs(f1.z); Bs[nc + 7][kr] = f2bs(f1.w);
        }
        __syncthreads();

        s8v a[4], b[4];
#pragma unroll
        for (int i = 0; i < 4; i++) a[i] = *(s8v*)&As[wm * 64 + i * 16 + m16][quad * 8];
#pragma unroll
        for (int j = 0; j < 4; j++) b[j] = *(s8v*)&Bs[wn * 64 + j * 16 + m16][quad * 8];
#pragma unroll
        for (int i = 0; i < 4; i++)
#pragma unroll
            for (int j = 0; j < 4; j++) acc[i][j] = MFMA16(a[i], b[j], acc[i][j]);
        __syncthreads();
    }

#pragma unroll
    for (int i = 0; i < 4; i++)
#pragma unroll
        for (int j = 0; j < 4; j++)
#pragma unroll
            for (int r = 0; r < 4; r++) {
                int row = bm * 128 + wm * 64 + i * 16 + quad * 4 + r;
                int col = bn * 128 + wn * 64 + j * 16 + m16;
                if constexpr (std::is_same<CT, float>::value)
                    C[(size_t)row * N + col] = acc[i][j][r];
                else
                    C[(size_t)row * N + col] = __float2bfloat16(acc[i][j][r]);
            }
}

// ---------------------------------------------------------------------------
// RoPE in-place on bf16 Q and K; freqs are fp32. One thread per (s,h,pair).
// ---------------------------------------------------------------------------
__global__ void rope_kernel(bf16* __restrict__ Q, bf16* __restrict__ K,
                            const float* __restrict__ fc, const float* __restrict__ fs) {
    int tid = blockIdx.x * blockDim.x + threadIdx.x;   // 0 .. 2048*2048-1
    int s = tid >> 11;
    int r = tid & 2047;      // h*64 + i
    int i = r & 63;
    float c  = fc[s * 64 + i];
    float sn = fs[s * 64 + i];
    size_t idx = (size_t)s * DIM + 2 * r;
    float qre = __bfloat162float(Q[idx]), qim = __bfloat162float(Q[idx + 1]);
    Q[idx]     = __float2bfloat16(qre * c - qim * sn);
    Q[idx + 1] = __float2bfloat16(qre * sn + qim * c);
    float kre = __bfloat162float(K[idx]), kim = __bfloat162float(K[idx + 1]);
    K[idx]     = __float2bfloat16(kre * c - kim * sn);
    K[idx + 1] = __float2bfloat16(kre * sn + kim * c);
}

// ---------------------------------------------------------------------------
// Flash attention (causal). Grid: (qb=32 blocks of 64 q-rows, h=32 heads).
// 256 threads = 4 waves; wave w owns q-rows [w*16, w*16+16).
// K-tile = 64 keys/iter. Q,K,V bf16 [SEQ][DIM]; V transposed in LDS.
// ---------------------------------------------------------------------------
__global__ __launch_bounds__(256) void attn_kernel(const bf16* __restrict__ Q,
                                                   const bf16* __restrict__ K,
                                                   const bf16* __restrict__ V,
                                                   bf16* __restrict__ O) {
    __shared__ short Ks[64][136];   // keys x hd (+8 pad)
    __shared__ short Vs[128][72];   // hd-col x keys (+8 pad)
    __shared__ short Ps[64][72];    // q-rows x keys (+8 pad)

    const int qb = blockIdx.x, h = blockIdx.y;
    const int tid  = threadIdx.x;
    const int w    = tid >> 6;
    const int lane = tid & 63;
    const int m16  = lane & 15;
    const int quad = lane >> 4;
    const float scale = 0.08838834764831845f;   // 1/sqrt(128)

    s8v aq[4];
    {
        const bf16* qp = Q + (size_t)(qb * 64 + w * 16 + m16) * DIM + h * HD + quad * 8;
#pragma unroll
        for (int ks = 0; ks < 4; ks++) aq[ks] = *(const s8v*)(qp + ks * 32);
    }

    f4v acc[8] = {};
    float mrow[4] = {-1e30f, -1e30f, -1e30f, -1e30f};
    float lrow[4] = {};

    for (int kt = 0; kt <= qb; kt++) {
#pragma unroll
        for (int v = tid; v < 1024; v += 256) {
            int n = v >> 4, kcol = (v & 15) * 8;
            *(s8v*)&Ks[n][kcol] =
                *(const s8v*)(K + (size_t)(kt * 64 + n) * DIM + h * HD + kcol);
        }
#pragma unroll
        for (int v = tid; v < 1024; v += 256) {
            int kr = v >> 4;            // key 0..63
            int nc = (v & 15) * 8;      // col 0..120
            s8v tmp = *(const s8v*)(V + (size_t)(kt * 64 + kr) * DIM + h * HD + nc);
#pragma unroll
            for (int e = 0; e < 8; e++) Vs[nc + e][kr] = tmp[e];
        }
        __syncthreads();

        f4v sc[4] = {};
#pragma unroll
        for (int j = 0; j < 4; j++)
#pragma unroll
            for (int ks = 0; ks < 4; ks++) {
                s8v bk = *(s8v*)&Ks[j * 16 + m16][ks * 32 + quad * 8];
                sc[j] = MFMA16(aq[ks], bk, sc[j]);
            }

        const bool diag = (kt == qb);
#pragma unroll
        for (int j = 0; j < 4; j++)
#pragma unroll
            for (int r = 0; r < 4; r++) {
                float sv = sc[j][r] * scale;
                if (diag && (j * 16 + m16) > (w * 16 + quad * 4 + r)) sv = -1e30f;
                sc[j][r] = sv;
            }

#pragma unroll
        for (int r = 0; r < 4; r++) {
            float mx = fmaxf(fmaxf(sc[0][r], sc[1][r]), fmaxf(sc[2][r], sc[3][r]));
#pragma unroll
            for (int off = 1; off < 16; off <<= 1) mx = fmaxf(mx, __shfl_xor(mx, off, 64));
            float mn    = fmaxf(mrow[r], mx);
            float alpha = __expf(mrow[r] - mn);
            mrow[r] = mn;
            float rs = 0.f;
#pragma unroll
            for (int j = 0; j < 4; j++) {
                float p = __expf(sc[j][r] - mn);
                sc[j][r] = p;
                rs += p;
            }
#pragma unroll
            for (int off = 1; off < 16; off <<= 1) rs += __shfl_xor(rs, off, 64);
            lrow[r] = lrow[r] * alpha + rs;
#pragma unroll
            for (int jo = 0; jo < 8; jo++) acc[jo][r] = acc[jo][r] * alpha;
        }

#pragma unroll
        for (int j = 0; j < 4; j++)
#pragma unroll
            for (int r = 0; r < 4; r++)
                Ps[w * 16 + quad * 4 + r][j * 16 + m16] = f2bs(sc[j][r]);
        __syncthreads();

#pragma unroll
        for (int ks2 = 0; ks2 < 2; ks2++) {
            s8v ap = *(s8v*)&Ps[w * 16 + m16][ks2 * 32 + quad * 8];
#pragma unroll
            for (int jo = 0; jo < 8; jo++) {
                s8v bv = *(s8v*)&Vs[jo * 16 + m16][ks2 * 32 + quad * 8];
                acc[jo] = MFMA16(ap, bv, acc[jo]);
            }
        }
        __syncthreads();
    }

#pragma unroll
    for (int jo = 0; jo < 8; jo++)
#pragma unroll
        for (int r = 0; r < 4; r++) {
            float o = acc[jo][r] / fmaxf(lrow[r], 1e-30f);
            int row = qb * 64 + w * 16 + quad * 4 + r;
            int col = h * HD + jo * 16 + m16;
            O[(size_t)row * DIM + col] = __float2bfloat16(o);
        }
}

// ---------------------------------------------------------------------------
extern "C" void kernel_launch(void* const* d_in, const int* in_sizes, int n_in,
                              void* d_out, int out_size, void* d_ws, size_t ws_size,
                              hipStream_t stream) {
    const float* x  = (const float*)d_in[0];
    const float* wq = (const float*)d_in[1];
    const float* wk = (const float*)d_in[2];
    const float* wv = (const float*)d_in[3];
    const float* wo = (const float*)d_in[4];
    const float* fc = (const float*)d_in[5];
    const float* fs = (const float*)d_in[6];
    // d_in[7] = mask (causal, recomputed analytically), d_in[8] = start_pos (0)

    float* out = (float*)d_out;

    const size_t SZ = (size_t)SEQ * DIM;   // elements
    bf16* Q  = (bf16*)d_ws;                // 64 MB total workspace (bf16)
    bf16* Kb = Q + SZ;
    bf16* V  = Kb + SZ;
    bf16* AO = V + SZ;

    dim3 gG(DIM / 128, SEQ / 128);         // GEMM grid (bn, bm)

    gemm_nat<float, bf16><<<gG, 256, 0, stream>>>(x, wq, Q,  SEQ, DIM, DIM);
    gemm_nat<float, bf16><<<gG, 256, 0, stream>>>(x, wk, Kb, SEQ, DIM, DIM);
    gemm_nat<float, bf16><<<gG, 256, 0, stream>>>(x, wv, V,  SEQ, DIM, DIM);

    rope_kernel<<<(SEQ * (DIM / 2)) / 256, 256, 0, stream>>>(Q, Kb, fc, fs);

    attn_kernel<<<dim3(SEQ / 64, NH), 256, 0, stream>>>(Q, Kb, V, AO);

    gemm_nat<bf16, float><<<gG, 256, 0, stream>>>(AO, wo, out, SEQ, DIM, DIM);
}

// Round 4
// 991.064 us; speedup vs baseline: 1.9370x; 1.9370x over previous
//
#include <hip/hip_runtime.h>
#include <hip/hip_bf16.h>
#include <type_traits>

typedef __hip_bfloat16 bf16;
typedef __attribute__((ext_vector_type(8))) short s8v;   // 8 x bf16 (16B)
typedef __attribute__((ext_vector_type(4))) short s4v;   // 4 x bf16 (8B)
typedef __attribute__((ext_vector_type(4))) float f4v;   // MFMA C/D frag

#define MFMA16(A, B, C) __builtin_amdgcn_mfma_f32_16x16x32_bf16((A), (B), (C), 0, 0, 0)

constexpr int SEQ = 2048;
constexpr int DIM = 4096;
constexpr int NH  = 32;
constexpr int HD  = 128;

__device__ __forceinline__ short f2bs(float f) {
    __hip_bfloat16_raw r = __float2bfloat16(f);
    return (short)r.x;
}

// async global->LDS, 16B per lane. HW semantics: wave-uniform LDS base +
// lane*16; lane i's global data lands at base + i*16.
__device__ __forceinline__ void ld_g2l(const bf16* g, bf16* l) {
    __builtin_amdgcn_global_load_lds(
        (const __attribute__((address_space(1))) void*)g,
        (__attribute__((address_space(3))) void*)l, 16, 0, 0);
}

// ---------------------------------------------------------------------------
// fp32 -> bf16 elementwise convert (float4 loads)
// ---------------------------------------------------------------------------
__global__ void convert_bf16(const float* __restrict__ s, bf16* __restrict__ d) {
    int i = blockIdx.x * blockDim.x + threadIdx.x;
    float4 f = ((const float4*)s)[i];
    s4v o;
    o[0] = f2bs(f.x); o[1] = f2bs(f.y); o[2] = f2bs(f.z); o[3] = f2bs(f.w);
    *(s4v*)(d + (size_t)i * 4) = o;
}

// ---------------------------------------------------------------------------
// fp32 [R][C] -> bf16 [C][R] transpose + convert (for weights -> [N][K])
// ---------------------------------------------------------------------------
__global__ void convt_bf16(const float* __restrict__ src, bf16* __restrict__ dst,
                           int R, int C) {
    __shared__ float t[32][33];
    int c0 = blockIdx.x * 32, r0 = blockIdx.y * 32;
    int tx = threadIdx.x, ty = threadIdx.y;
#pragma unroll
    for (int i = 0; i < 4; i++)
        t[ty + 8 * i][tx] = src[(size_t)(r0 + ty + 8 * i) * C + c0 + tx];
    __syncthreads();
#pragma unroll
    for (int i = 0; i < 4; i++)
        dst[(size_t)(c0 + ty + 8 * i) * R + r0 + tx] = __float2bfloat16(t[tx][ty + 8 * i]);
}

// ---------------------------------------------------------------------------
// Fast GEMM (m97 structure): C[M,N] = A[M,K] * Bt[N,K]^T, bf16 in, CT out.
// 128x128 tile, BK=32, global_load_lds width=16 staging, unpadded LDS.
// ---------------------------------------------------------------------------
template <typename CT>
__global__ __launch_bounds__(256) void gemm_lds(const bf16* __restrict__ A,
                                                const bf16* __restrict__ Bt,
                                                CT* __restrict__ C,
                                                int M, int N, int K) {
    __shared__ bf16 As[128 * 32];   // row-major [row][32k], 64B rows
    __shared__ bf16 Bs[128 * 32];
    const int tid  = threadIdx.x;
    const int lane = tid & 63;
    const int w    = tid >> 6;
    const int m16  = lane & 15;
    const int quad = lane >> 4;
    const int wm   = w >> 1, wn = w & 1;
    const int bm   = blockIdx.y, bn = blockIdx.x;

    const bf16* Ab = A  + (size_t)bm * 128 * K;
    const bf16* Bb = Bt + (size_t)bn * 128 * K;

    const int lrow = lane >> 2;          // 0..15
    const int lcol = (lane & 3) * 8;     // 0,8,16,24

    f4v acc[4][4] = {};

    for (int k0 = 0; k0 < K; k0 += 32) {
#pragma unroll
        for (int rep = 0; rep < 2; rep++) {
            int c = w * 2 + rep;         // chunk 0..7 = rows c*16..c*16+15
            ld_g2l(Ab + (size_t)(c * 16 + lrow) * K + k0 + lcol, As + c * 512);
            ld_g2l(Bb + (size_t)(c * 16 + lrow) * K + k0 + lcol, Bs + c * 512);
        }
        __syncthreads();

        s8v a[4], b[4];
#pragma unroll
        for (int i = 0; i < 4; i++)
            a[i] = *(s8v*)(As + (wm * 64 + i * 16 + m16) * 32 + quad * 8);
#pragma unroll
        for (int j = 0; j < 4; j++)
            b[j] = *(s8v*)(Bs + (wn * 64 + j * 16 + m16) * 32 + quad * 8);
#pragma unroll
        for (int i = 0; i < 4; i++)
#pragma unroll
            for (int j = 0; j < 4; j++) acc[i][j] = MFMA16(a[i], b[j], acc[i][j]);
        __syncthreads();
    }

#pragma unroll
    for (int i = 0; i < 4; i++)
#pragma unroll
        for (int j = 0; j < 4; j++)
#pragma unroll
            for (int r = 0; r < 4; r++) {
                int row = bm * 128 + wm * 64 + i * 16 + quad * 4 + r;
                int col = bn * 128 + wn * 64 + j * 16 + m16;
                if constexpr (std::is_same<CT, float>::value)
                    C[(size_t)row * N + col] = acc[i][j][r];
                else
                    C[(size_t)row * N + col] = __float2bfloat16(acc[i][j][r]);
            }
}

// ---------------------------------------------------------------------------
// Fallback GEMM (round-3, fp32 B with in-loop conversion) — used only if
// ws_size is too small for the bf16-conversion buffers.
// ---------------------------------------------------------------------------
template <typename AT, typename CT>
__global__ __launch_bounds__(256) void gemm_nat(const AT* __restrict__ A,
                                                const float* __restrict__ B,
                                                CT* __restrict__ C,
                                                int M, int N, int K) {
    __shared__ short As[128][40];
    __shared__ short Bs[128][40];
    const int tid  = threadIdx.x;
    const int lane = tid & 63;
    const int w    = tid >> 6;
    const int m16  = lane & 15;
    const int quad = lane >> 4;
    const int wm   = w >> 1, wn = w & 1;
    const int bm   = blockIdx.y, bn = blockIdx.x;

    const AT* Ab = A + (size_t)bm * 128 * K;

    f4v acc[4][4] = {};
    const int r0 = tid >> 2;
    const int kc = (tid & 3) * 8;

    for (int k0 = 0; k0 < K; k0 += 32) {
        if constexpr (std::is_same<AT, float>::value) {
#pragma unroll
            for (int half = 0; half < 2; half++) {
                const float* src = Ab + (size_t)(r0 + 64 * half) * K + k0 + kc;
                float4 f0 = *(const float4*)(src);
                float4 f1 = *(const float4*)(src + 4);
                s8v t;
                t[0] = f2bs(f0.x); t[1] = f2bs(f0.y); t[2] = f2bs(f0.z); t[3] = f2bs(f0.w);
                t[4] = f2bs(f1.x); t[5] = f2bs(f1.y); t[6] = f2bs(f1.z); t[7] = f2bs(f1.w);
                *(s8v*)&As[r0 + 64 * half][kc] = t;
            }
        } else {
            *(s8v*)&As[r0][kc]      = *(const s8v*)(Ab + (size_t)r0 * K + k0 + kc);
            *(s8v*)&As[r0 + 64][kc] = *(const s8v*)(Ab + (size_t)(r0 + 64) * K + k0 + kc);
        }
#pragma unroll
        for (int v = tid; v < 512; v += 256) {
            int kr = v >> 4;
            int nc = (v & 15) * 8;
            const float* src = B + (size_t)(k0 + kr) * N + bn * 128 + nc;
            float4 f0 = *(const float4*)(src);
            float4 f1 = *(const float4*)(src + 4);
            Bs[nc + 0][kr] = f2bs(f0.x); Bs[nc + 1][kr] = f2bs(f0.y);
            Bs[nc + 2][kr] = f2bs(f0.z); Bs[nc + 3][kr] = f2bs(f0.w);
            Bs[nc + 4][kr] = f2bs(f1.x); Bs[nc + 5][kr] = f2bs(f1.y);
            Bs[nc + 6][kr] = f2bs(f1.z); Bs[nc + 7][kr] = f2bs(f1.w);
        }
        __syncthreads();

        s8v a[4], b[4];
#pragma unroll
        for (int i = 0; i < 4; i++) a[i] = *(s8v*)&As[wm * 64 + i * 16 + m16][quad * 8];
#pragma unroll
        for (int j = 0; j < 4; j++) b[j] = *(s8v*)&Bs[wn * 64 + j * 16 + m16][quad * 8];
#pragma unroll
        for (int i = 0; i < 4; i++)
#pragma unroll
            for (int j = 0; j < 4; j++) acc[i][j] = MFMA16(a[i], b[j], acc[i][j]);
        __syncthreads();
    }

#pragma unroll
    for (int i = 0; i < 4; i++)
#pragma unroll
        for (int j = 0; j < 4; j++)
#pragma unroll
            for (int r = 0; r < 4; r++) {
                int row = bm * 128 + wm * 64 + i * 16 + quad * 4 + r;
                int col = bn * 128 + wn * 64 + j * 16 + m16;
                if constexpr (std::is_same<CT, float>::value)
                    C[(size_t)row * N + col] = acc[i][j][r];
                else
                    C[(size_t)row * N + col] = __float2bfloat16(acc[i][j][r]);
            }
}

// ---------------------------------------------------------------------------
// RoPE in-place on bf16 Q and K; freqs fp32.
// ---------------------------------------------------------------------------
__global__ void rope_kernel(bf16* __restrict__ Q, bf16* __restrict__ K,
                            const float* __restrict__ fc, const float* __restrict__ fs) {
    int tid = blockIdx.x * blockDim.x + threadIdx.x;
    int s = tid >> 11;
    int r = tid & 2047;
    int i = r & 63;
    float c  = fc[s * 64 + i];
    float sn = fs[s * 64 + i];
    size_t idx = (size_t)s * DIM + 2 * r;
    float qre = __bfloat162float(Q[idx]), qim = __bfloat162float(Q[idx + 1]);
    Q[idx]     = __float2bfloat16(qre * c - qim * sn);
    Q[idx + 1] = __float2bfloat16(qre * sn + qim * c);
    float kre = __bfloat162float(K[idx]), kim = __bfloat162float(K[idx + 1]);
    K[idx]     = __float2bfloat16(kre * c - kim * sn);
    K[idx + 1] = __float2bfloat16(kre * sn + kim * c);
}

// ---------------------------------------------------------------------------
// Flash attention (causal). Grid: (32 qb-blocks DESCENDING, 32 heads).
// V staged by gather (lane<->key) -> conflict-free transpose stores.
// ---------------------------------------------------------------------------
__global__ __launch_bounds__(256) void attn_kernel(const bf16* __restrict__ Q,
                                                   const bf16* __restrict__ K,
                                                   const bf16* __restrict__ V,
                                                   bf16* __restrict__ O) {
    __shared__ short Ks[64][136];
    __shared__ short Vs[128][72];
    __shared__ short Ps[64][72];

    const int qb = (int)gridDim.x - 1 - (int)blockIdx.x;   // long blocks first
    const int h  = blockIdx.y;
    const int tid  = threadIdx.x;
    const int w    = tid >> 6;
    const int lane = tid & 63;
    const int m16  = lane & 15;
    const int quad = lane >> 4;
    const float scale = 0.08838834764831845f;   // 1/sqrt(128)

    s8v aq[4];
    {
        const bf16* qp = Q + (size_t)(qb * 64 + w * 16 + m16) * DIM + h * HD + quad * 8;
#pragma unroll
        for (int ks = 0; ks < 4; ks++) aq[ks] = *(const s8v*)(qp + ks * 32);
    }

    f4v acc[8] = {};
    float mrow[4] = {-1e30f, -1e30f, -1e30f, -1e30f};
    float lrow[4] = {};

    for (int kt = 0; kt <= qb; kt++) {
        // K tile: coalesced row copy
#pragma unroll
        for (int v = tid; v < 1024; v += 256) {
            int n = v >> 4, kcol = (v & 15) * 8;
            *(s8v*)&Ks[n][kcol] =
                *(const s8v*)(K + (size_t)(kt * 64 + n) * DIM + h * HD + kcol);
        }
        // V tile: gather (lane<->key) -> LDS stores walk consecutive shorts
#pragma unroll
        for (int v = tid; v < 1024; v += 256) {
            int kr = v & 63;            // key = lane (varies across lanes)
            int cg = (v >> 6) * 8;      // col group (wave-uniform per instr)
            s8v tmp = *(const s8v*)(V + (size_t)(kt * 64 + kr) * DIM + h * HD + cg);
#pragma unroll
            for (int e = 0; e < 8; e++) Vs[cg + e][kr] = tmp[e];
        }
        __syncthreads();

        f4v sc[4] = {};
#pragma unroll
        for (int j = 0; j < 4; j++)
#pragma unroll
            for (int ks = 0; ks < 4; ks++) {
                s8v bk = *(s8v*)&Ks[j * 16 + m16][ks * 32 + quad * 8];
                sc[j] = MFMA16(aq[ks], bk, sc[j]);
            }

        const bool diag = (kt == qb);
#pragma unroll
        for (int j = 0; j < 4; j++)
#pragma unroll
            for (int r = 0; r < 4; r++) {
                float sv = sc[j][r] * scale;
                if (diag && (j * 16 + m16) > (w * 16 + quad * 4 + r)) sv = -1e30f;
                sc[j][r] = sv;
            }

#pragma unroll
        for (int r = 0; r < 4; r++) {
            float mx = fmaxf(fmaxf(sc[0][r], sc[1][r]), fmaxf(sc[2][r], sc[3][r]));
#pragma unroll
            for (int off = 1; off < 16; off <<= 1) mx = fmaxf(mx, __shfl_xor(mx, off, 64));
            float mn    = fmaxf(mrow[r], mx);
            float alpha = __expf(mrow[r] - mn);
            mrow[r] = mn;
            float rs = 0.f;
#pragma unroll
            for (int j = 0; j < 4; j++) {
                float p = __expf(sc[j][r] - mn);
                sc[j][r] = p;
                rs += p;
            }
#pragma unroll
            for (int off = 1; off < 16; off <<= 1) rs += __shfl_xor(rs, off, 64);
            lrow[r] = lrow[r] * alpha + rs;
#pragma unroll
            for (int jo = 0; jo < 8; jo++) acc[jo][r] = acc[jo][r] * alpha;
        }

#pragma unroll
        for (int j = 0; j < 4; j++)
#pragma unroll
            for (int r = 0; r < 4; r++)
                Ps[w * 16 + quad * 4 + r][j * 16 + m16] = f2bs(sc[j][r]);
        __syncthreads();

#pragma unroll
        for (int ks2 = 0; ks2 < 2; ks2++) {
            s8v ap = *(s8v*)&Ps[w * 16 + m16][ks2 * 32 + quad * 8];
#pragma unroll
            for (int jo = 0; jo < 8; jo++) {
                s8v bv = *(s8v*)&Vs[jo * 16 + m16][ks2 * 32 + quad * 8];
                acc[jo] = MFMA16(ap, bv, acc[jo]);
            }
        }
        __syncthreads();
    }

#pragma unroll
    for (int jo = 0; jo < 8; jo++)
#pragma unroll
        for (int r = 0; r < 4; r++) {
            float o = acc[jo][r] / fmaxf(lrow[r], 1e-30f);
            int row = qb * 64 + w * 16 + quad * 4 + r;
            int col = h * HD + jo * 16 + m16;
            O[(size_t)row * DIM + col] = __float2bfloat16(o);
        }
}

// ---------------------------------------------------------------------------
extern "C" void kernel_launch(void* const* d_in, const int* in_sizes, int n_in,
                              void* d_out, int out_size, void* d_ws, size_t ws_size,
                              hipStream_t stream) {
    const float* x  = (const float*)d_in[0];
    const float* wq = (const float*)d_in[1];
    const float* wk = (const float*)d_in[2];
    const float* wv = (const float*)d_in[3];
    const float* wo = (const float*)d_in[4];
    const float* fc = (const float*)d_in[5];
    const float* fs = (const float*)d_in[6];

    float* out = (float*)d_out;

    const size_t SZ = (size_t)SEQ * DIM;
    const size_t WZ = (size_t)DIM * DIM;
    bf16* Q  = (bf16*)d_ws;
    bf16* Kb = Q + SZ;
    bf16* V  = Kb + SZ;
    bf16* AO = V + SZ;

    dim3 gG(DIM / 128, SEQ / 128);
    const size_t need = (5 * SZ + WZ) * sizeof(bf16);   // 112 MB

    if (ws_size >= need) {
        bf16* xb = AO + SZ;        // [SEQ][DIM] bf16
        bf16* wb = xb + SZ;        // [DIM][DIM] bf16, transposed weight, reused

        dim3 tB(32, 8), tGw(DIM / 32, DIM / 32);

        convert_bf16<<<(int)(SZ / 4 / 256), 256, 0, stream>>>(x, xb);

        convt_bf16<<<tGw, tB, 0, stream>>>(wq, wb, DIM, DIM);
        gemm_lds<bf16><<<gG, 256, 0, stream>>>(xb, wb, Q, SEQ, DIM, DIM);
        convt_bf16<<<tGw, tB, 0, stream>>>(wk, wb, DIM, DIM);
        gemm_lds<bf16><<<gG, 256, 0, stream>>>(xb, wb, Kb, SEQ, DIM, DIM);
        convt_bf16<<<tGw, tB, 0, stream>>>(wv, wb, DIM, DIM);
        gemm_lds<bf16><<<gG, 256, 0, stream>>>(xb, wb, V, SEQ, DIM, DIM);

        rope_kernel<<<(SEQ * (DIM / 2)) / 256, 256, 0, stream>>>(Q, Kb, fc, fs);
        attn_kernel<<<dim3(SEQ / 64, NH), 256, 0, stream>>>(Q, Kb, V, AO);

        convt_bf16<<<tGw, tB, 0, stream>>>(wo, wb, DIM, DIM);
        gemm_lds<float><<<gG, 256, 0, stream>>>(AO, wb, out, SEQ, DIM, DIM);
    } else {
        gemm_nat<float, bf16><<<gG, 256, 0, stream>>>(x, wq, Q,  SEQ, DIM, DIM);
        gemm_nat<float, bf16><<<gG, 256, 0, stream>>>(x, wk, Kb, SEQ, DIM, DIM);
        gemm_nat<float, bf16><<<gG, 256, 0, stream>>>(x, wv, V,  SEQ, DIM, DIM);
        rope_kernel<<<(SEQ * (DIM / 2)) / 256, 256, 0, stream>>>(Q, Kb, fc, fs);
        attn_kernel<<<dim3(SEQ / 64, NH), 256, 0, stream>>>(Q, Kb, V, AO);
        gemm_nat<bf16, float><<<gG, 256, 0, stream>>>(AO, wo, out, SEQ, DIM, DIM);
    }
}